// Round 13
// baseline (286.121 us; speedup 1.0000x reference)
//
#include <hip/hip_runtime.h>
#include <stdint.h>

#define BATCH   8
#define LEN0    8192
#define EMB     768
#define POOLED  512    // LEN0 >> 4
#define NJC     16     // j-chunks per level in rank phase
#define PL      (BATCH * LEN0)

struct __align__(16) Rec { uint32_t iA, iB; float w0, w1; };

// ---------------------------------------------------------------------------
// ws layout (bytes):
//   scA    : BATCH*LEN0 f32        @ 0x000000  (256 KiB)
//   scB    : BATCH*LEN0 f32        @ 0x040000
//   rank16 : BATCH*LEN0 u16        @ 0x080000  (128 KiB)
//   ior16  : BATCH*LEN0 u16        @ 0x0A0000  (128 KiB)
//   rec0   : 4096*8 Rec            @ 0x0C0000  (512 KiB)
//   rec1   : 2048*8 Rec            @ 0x140000  (256 KiB)
//   rec2   : 1024*8 Rec            @ 0x180000  (128 KiB)
//   rec3   :  512*8 Rec            @ 0x1A0000  ( 64 KiB)
//   rankp  : NJC planes BATCH*LEN0 u16 @ 0x1C0000 (2 MiB)
//   csum   : BATCH*32 u32          @ 0x3C0000  (1 KiB)
//   ticket : 4 levels * 8*8*16 u32 @ 0x3C4000  (16 KiB, memsetAsync'd)
// ---------------------------------------------------------------------------

// Bit-faithful replication of numpy's SIMD float32 exp — DO NOT TOUCH.
// (Round 5 proved this exact sequence makes ranks match the numpy golden.)
__device__ __forceinline__ float npy_expf(float x) {
    const float q = rintf(__fmul_rn(x, 1.44269504088896341f)); // LOG2EF
    float r = __fmaf_rn(q, -0.693359375f, x);       // fnmadd(q, C1, x)
    r = __fmaf_rn(q, 2.12194440e-4f, r);            // fnmadd(q, C2, x)
    const float r2 = __fmul_rn(r, r);
    float p = 1.9875691500E-4f;
    p = __fmaf_rn(p, r, 1.3981999507E-3f);
    p = __fmaf_rn(p, r, 8.3334519073E-3f);
    p = __fmaf_rn(p, r, 4.1665795894E-2f);
    p = __fmaf_rn(p, r, 1.6666665459E-1f);
    p = __fmaf_rn(p, r, 5.0000001201E-1f);
    p = __fmaf_rn(p, r2, r);
    p = __fadd_rn(p, 1.0f);
    const int qi = (int)q;
    const float sc = __uint_as_float((uint32_t)((qi + 127) << 23));
    return __fmul_rn(p, sc);
}

// Fused rank + finalize (split-K ticket pattern).
// grid (L/1024, NJC, BATCH), 256 thr.  Each block ranks its 1024-i chunk
// against its j-chunk (stable ties) -> rankp plane; the LAST arriving block
// per (b, i-chunk) sums all NJC planes -> rank16, scatters ior16, and
// wave-reduces per-256-chunk top-flag counts -> csum.  The sum is an
// integer commutative reduction over fixed values -> deterministic output.
__global__ __launch_bounds__(256) void k_rankf(const float* __restrict__ sc,
                                               uint16_t* __restrict__ rankp,
                                               uint16_t* __restrict__ rank16,
                                               uint16_t* __restrict__ ior16,
                                               uint32_t* __restrict__ csum,
                                               uint32_t* __restrict__ ticket,
                                               int L, int C) {
    __shared__ float keys[512];            // C <= 512
    __shared__ uint32_t amLast;
    const int b     = blockIdx.z;
    const int jc    = blockIdx.y;
    const int base  = b * LEN0;
    const int ibase = blockIdx.x * 1024;
    const int jb    = jc * C;
    const int tid   = threadIdx.x;

    for (int j = tid; j < C; j += 256)
        keys[j] = sc[base + jb + j];
    __syncthreads();

    const int i0 = ibase + tid * 4;
    const float4 mev = *(const float4*)&sc[base + i0];
    const float me[4] = {mev.x, mev.y, mev.z, mev.w};
    uint32_t cnt[4] = {0, 0, 0, 0};
    if (jb + C <= ibase) {             // all j < i: ties count
        for (int j = 0; j < C; j += 4) {
            const float4 kv = *(const float4*)&keys[j];
            #pragma unroll
            for (int m = 0; m < 4; m++)
                cnt[m] += (kv.x >= me[m]) + (kv.y >= me[m]) +
                          (kv.z >= me[m]) + (kv.w >= me[m]);
        }
    } else if (jb >= ibase + 1024) {   // all j > i: ties don't count
        for (int j = 0; j < C; j += 4) {
            const float4 kv = *(const float4*)&keys[j];
            #pragma unroll
            for (int m = 0; m < 4; m++)
                cnt[m] += (kv.x > me[m]) + (kv.y > me[m]) +
                          (kv.z > me[m]) + (kv.w > me[m]);
        }
    } else {                           // diagonal: full stable predicate
        for (int j = 0; j < C; j += 4) {
            const float4 kv = *(const float4*)&keys[j];
            const int jj = jb + j;
            #pragma unroll
            for (int m = 0; m < 4; m++) {
                const int i = i0 + m;
                cnt[m] += ((kv.x > me[m]) || (kv.x == me[m] && (jj    ) < i))
                        + ((kv.y > me[m]) || (kv.y == me[m] && (jj + 1) < i))
                        + ((kv.z > me[m]) || (kv.z == me[m] && (jj + 2) < i))
                        + ((kv.w > me[m]) || (kv.w == me[m] && (jj + 3) < i));
            }
        }
    }
    *(ushort4*)&rankp[(size_t)jc * PL + base + i0] =
        make_ushort4((uint16_t)cnt[0], (uint16_t)cnt[1],
                     (uint16_t)cnt[2], (uint16_t)cnt[3]);

    // --- ticket: last block of the NJC j-chunks finalizes this i-chunk ---
    __threadfence();                   // release this thread's rankp writes
    __syncthreads();                   // all block writes precede the RMW
    if (tid == 0) {
        const uint32_t t = __hip_atomic_fetch_add(
            &ticket[(b * 8 + blockIdx.x) * 16], 1u,
            __ATOMIC_ACQ_REL, __HIP_MEMORY_SCOPE_AGENT);
        amLast = (t == NJC - 1) ? 1u : 0u;
    }
    __syncthreads();
    if (!amLast) return;
    __threadfence();                   // acquire: see other CUs' rankp

    uint32_t r0 = 0, r1 = 0, r2 = 0, r3 = 0;
    #pragma unroll
    for (int pl = 0; pl < NJC; pl++) {
        const ushort4 v = *(const ushort4*)&rankp[(size_t)pl * PL + base + i0];
        r0 += v.x; r1 += v.y; r2 += v.z; r3 += v.w;
    }
    *(ushort4*)&rank16[base + i0] =
        make_ushort4((uint16_t)r0, (uint16_t)r1, (uint16_t)r2, (uint16_t)r3);
    ior16[base + r0] = (uint16_t)(i0);
    ior16[base + r1] = (uint16_t)(i0 + 1);
    ior16[base + r2] = (uint16_t)(i0 + 2);
    ior16[base + r3] = (uint16_t)(i0 + 3);

    const uint32_t half = (uint32_t)(L / 2);
    uint32_t f = (r0 < half) + (r1 < half) + (r2 < half) + (r3 < half);
    #pragma unroll
    for (int off = 32; off > 0; off >>= 1)
        f += __shfl_down(f, off, 64);
    if ((tid & 63) == 0)               // wave w covers i [ibase+w*256, +256)
        csum[b * 32 + blockIdx.x * 4 + (tid >> 6)] = f;
}

// Wide pair phase (verbatim round 11): chunk dst-base from csum, in-block
// flag scan, softmax (NUMERICS FROZEN, round 5), Rec write.
// grid (L/256, BATCH), 256 thr.
__global__ __launch_bounds__(256) void k_pairx(const float* __restrict__ sc_cur,
                                               float* __restrict__ sc_nxt,
                                               const uint16_t* __restrict__ rank16,
                                               const uint16_t* __restrict__ ior16,
                                               const uint32_t* __restrict__ csum,
                                               Rec* __restrict__ rec,
                                               int L) {
    __shared__ uint32_t cs[32];
    __shared__ uint32_t part[256];
    const int b    = blockIdx.y;
    const int base = b * LEN0;
    const int c    = blockIdx.x;
    const int tid  = threadIdx.x;
    const int i    = c * 256 + tid;
    const uint32_t half = (uint32_t)(L / 2);

    if (tid < c) cs[tid] = csum[b * 32 + tid];
    const uint32_t r = rank16[base + i];
    const uint32_t flag = (r < half) ? 1u : 0u;
    part[tid] = flag;
    __syncthreads();

    uint32_t dstBase = 0;
    for (int t = 0; t < c; t++) dstBase += cs[t];   // LDS broadcast reads

    for (int off = 1; off < 256; off <<= 1) {       // Hillis-Steele inclusive
        uint32_t v = part[tid];
        uint32_t add = (tid >= off) ? part[tid - off] : 0u;
        __syncthreads();
        part[tid] = v + add;
        __syncthreads();
    }
    if (!flag) return;
    const uint32_t dst = dstBase + part[tid] - 1u;  // exclusive within chunk

    const uint32_t p = ior16[base + (uint32_t)(L - 1) - r];
    const float s0 = sc_cur[base + i];
    const float s1 = sc_cur[base + p];
    // np.power(2.0, s): glibc powf (correctly rounded); exp2 in double
    // rounded to f32 reproduces it.
    const float p0 = (float)exp2((double)s0);
    const float p1 = (float)exp2((double)s1);
    const float mx = fmaxf(p0, p1);
    const float d0 = __fsub_rn(p0, mx);
    const float d1 = __fsub_rn(p1, mx);
    const float e0 = npy_expf(d0);
    const float e1 = npy_expf(d1);
    const float den = __fadd_rn(e0, e1);
    const float w0 = __fdiv_rn(e0, den);
    const float w1 = __fdiv_rn(e1, den);
    sc_nxt[base + dst] = __fadd_rn(__fmul_rn(s0, w0), __fmul_rn(s1, w1));

    Rec rc; rc.iA = (uint32_t)i; rc.iB = p; rc.w0 = w0; rc.w1 = w1;
    rec[(size_t)b * half + dst] = rc;
}

// Final gather: expand 4-level pair tree -> 16 leaves (verified rounds 9-12).
__global__ __launch_bounds__(192)
void k_merge(const float* __restrict__ emb,
             const Rec* __restrict__ rec0, const Rec* __restrict__ rec1,
             const Rec* __restrict__ rec2, const Rec* __restrict__ rec3,
             const float* __restrict__ sc_fin, float* __restrict__ out) {
    __shared__ uint32_t sl[2][16];
    __shared__ float    sw[2][16];
    const int s = blockIdx.x;
    const int b = blockIdx.y;
    const int d = threadIdx.x;

    if (d == 0) {
        const Rec r = rec3[b * 512 + s];
        sl[0][0] = r.iA; sl[0][1] = r.iB;
        sw[0][0] = r.w0; sw[0][1] = r.w1;
    }
    __syncthreads();
    if (d < 2) {
        const Rec r = rec2[b * 1024 + sl[0][d]];
        sl[1][2*d] = r.iA; sl[1][2*d+1] = r.iB;
        sw[1][2*d]   = __fmul_rn(sw[0][d], r.w0);
        sw[1][2*d+1] = __fmul_rn(sw[0][d], r.w1);
    }
    __syncthreads();
    if (d < 4) {
        const Rec r = rec1[b * 2048 + sl[1][d]];
        sl[0][2*d] = r.iA; sl[0][2*d+1] = r.iB;
        sw[0][2*d]   = __fmul_rn(sw[1][d], r.w0);
        sw[0][2*d+1] = __fmul_rn(sw[1][d], r.w1);
    }
    __syncthreads();
    if (d < 8) {
        const Rec r = rec0[b * 4096 + sl[0][d]];   // iA/iB = original rows
        sl[1][2*d] = r.iA; sl[1][2*d+1] = r.iB;
        sw[1][2*d]   = __fmul_rn(sw[0][d], r.w0);
        sw[1][2*d+1] = __fmul_rn(sw[0][d], r.w1);
    }
    __syncthreads();

    const float* ebase = emb + (size_t)b * LEN0 * EMB;
    float4 acc = make_float4(0.f, 0.f, 0.f, 0.f);
    #pragma unroll
    for (int k = 0; k < 16; k++) {
        const float4 v = *(const float4*)(ebase + (size_t)sl[1][k] * EMB + d * 4);
        const float wk = sw[1][k];
        acc.x += wk * v.x; acc.y += wk * v.y; acc.z += wk * v.z; acc.w += wk * v.w;
    }
    *(float4*)(out + ((size_t)b * POOLED + s) * EMB + d * 4) = acc;
    if (d == 0)
        out[(size_t)BATCH * POOLED * EMB + b * POOLED + s] = sc_fin[b * LEN0 + s];
}

extern "C" void kernel_launch(void* const* d_in, const int* in_sizes, int n_in,
                              void* d_out, int out_size, void* d_ws, size_t ws_size,
                              hipStream_t stream) {
    const float* embs   = (const float*)d_in[0];
    const float* scores = (const float*)d_in[1];
    float* out = (float*)d_out;
    char* ws = (char*)d_ws;

    float*    scA    = (float*)(ws + 0x000000);
    float*    scB    = (float*)(ws + 0x040000);
    uint16_t* rank16 = (uint16_t*)(ws + 0x080000);
    uint16_t* ior16  = (uint16_t*)(ws + 0x0A0000);
    Rec*      rec0   = (Rec*)(ws + 0x0C0000);
    Rec*      rec1   = (Rec*)(ws + 0x140000);
    Rec*      rec2   = (Rec*)(ws + 0x180000);
    Rec*      rec3   = (Rec*)(ws + 0x1A0000);
    uint16_t* rankp  = (uint16_t*)(ws + 0x1C0000);
    uint32_t* csum   = (uint32_t*)(ws + 0x3C0000);
    uint32_t* ticket = (uint32_t*)(ws + 0x3C4000);

    // tickets: 4 levels x 8 i-chunks x 8 batches x 16-u32 stride = 16 KiB
    hipMemsetAsync(ticket, 0, 4 * 8 * 8 * 16 * 4, stream);

    const float* sc_in[4]  = {scores, scA, scB, scA};
    float*       sc_out[4] = {scA, scB, scA, scB};
    Rec*         recs[4]   = {rec0, rec1, rec2, rec3};

    int L = LEN0;
    for (int l = 0; l < 4; l++) {
        const int C = L / NJC;           // 512,256,128,64
        k_rankf<<<dim3(L / 1024, NJC, BATCH), 256, 0, stream>>>(
            sc_in[l], rankp, rank16, ior16, csum, ticket + l * 1024, L, C);
        k_pairx<<<dim3(L / 256, BATCH), 256, 0, stream>>>(
            sc_in[l], sc_out[l], rank16, ior16, csum, recs[l], L);
        L >>= 1;
    }

    k_merge<<<dim3(POOLED, BATCH), 192, 0, stream>>>(embs, rec0, rec1, rec2, rec3,
                                                     scB, out);
}